// Round 3
// baseline (1607.353 us; speedup 1.0000x reference)
//
#include <hip/hip_runtime.h>
#include <hip/hip_bf16.h>
#include <hip/hip_fp16.h>

// LSTM: S=2048, B=128, I=128, H=128, 4H=512
// out = [h_seq (S*B*H) | h_T (B*H) | c_T (B*H)], fp32
// ws  = x16 (S*B*I fp16) = 67 MB
//
// Round 3: FUSE the V.x matvec into the scan's latency shadow.
//  - step time has proven invariant (~1340 cy) across fdot2/MFMA/prefetch
//    variants -> the recurrence chain dominates and waves are ~50% idle.
//  - phase-1 GEMM (235 us) + 268 MB xg write + 268 MB xg read deleted.
//  - x pre-converted to f16 once (~40 us), V-frags in regs, xacc(s+1)
//    built during step s with 16 independent MFMAs; W-chain seeds its
//    accumulator with xacc (the +xg add vanishes into the MFMA C-input).

#define S_LEN 2048
#define BATCH 128
#define HID   128
#define G4    512

typedef _Float16 h8_t __attribute__((ext_vector_type(8)));
typedef float    f4_t __attribute__((ext_vector_type(4)));

#define MFMA16(A, B, C) __builtin_amdgcn_mfma_f32_16x16x32_f16((A), (B), (C), 0, 0, 0)

// ---------------------------------------------------------------------------
// x (f32) -> x16 (f16), 33.5M elems, memory-bound ~40 us
// ---------------------------------------------------------------------------
__global__ __launch_bounds__(256)
void x_cvt(const float* __restrict__ x, __half* __restrict__ x16)
{
    long i = ((long)blockIdx.x * 256 + threadIdx.x) * 8;
    const float4* p = (const float4*)(x + i);
    float4 v0 = p[0], v1 = p[1];
    h8_t h = { (_Float16)v0.x, (_Float16)v0.y, (_Float16)v0.z, (_Float16)v0.w,
               (_Float16)v1.x, (_Float16)v1.y, (_Float16)v1.z, (_Float16)v1.w };
    *(h8_t*)((_Float16*)x16 + i) = h;
}

// ---------------------------------------------------------------------------
__device__ __forceinline__ float fsig(float x) {
    return __builtin_amdgcn_rcpf(1.f + __expf(-x));
}
__device__ __forceinline__ float ftanh(float x) {
    return 1.f - 2.f * __builtin_amdgcn_rcpf(1.f + __expf(2.f * x));
}
__device__ __forceinline__ void bar() {
    asm volatile("s_waitcnt lgkmcnt(0)" ::: "memory");
    __builtin_amdgcn_s_barrier();
    asm volatile("" ::: "memory");
}

// One scan step. XUSE: xacc consumed this step (C-seed of the W-chain).
// XBLD: xacc built this step for step s+1 (V-MFMAs, off the critical chain).
// XF:   x16 frag slot holding x(s+1); refilled afterwards with x(SN).
#define LSTEP(S, XUSE, XBLD, XF, SN)                                           \
    {                                                                          \
        const int s = (S);                                                     \
        const h8_t* hb = (const h8_t*)(&h_buf[s & 1][0]);                      \
        h8_t hf0 = hb[quad], hf1 = hb[4 + quad], hf2 = hb[8 + quad],           \
             hf3 = hb[12 + quad];                                              \
        f4_t g0 = XUSE[0], g1 = XUSE[1], g2 = XUSE[2], g3 = XUSE[3];           \
        g0 = MFMA16(a[0][0], hf0, g0);  g1 = MFMA16(a[1][0], hf0, g1);         \
        g2 = MFMA16(a[2][0], hf0, g2);  g3 = MFMA16(a[3][0], hf0, g3);         \
        g0 = MFMA16(a[0][1], hf1, g0);  g1 = MFMA16(a[1][1], hf1, g1);         \
        g2 = MFMA16(a[2][1], hf1, g2);  g3 = MFMA16(a[3][1], hf1, g3);         \
        g0 = MFMA16(a[0][2], hf2, g0);  g1 = MFMA16(a[1][2], hf2, g1);         \
        g2 = MFMA16(a[2][2], hf2, g2);  g3 = MFMA16(a[3][2], hf2, g3);         \
        g0 = MFMA16(a[0][3], hf3, g0);  g1 = MFMA16(a[1][3], hf3, g1);         \
        g2 = MFMA16(a[2][3], hf3, g2);  g3 = MFMA16(a[3][3], hf3, g3);         \
        /* shadow: build xacc for step s+1 from XF = x(s+1) */                 \
        XBLD[0] = (f4_t)0.f; XBLD[1] = (f4_t)0.f;                              \
        XBLD[2] = (f4_t)0.f; XBLD[3] = (f4_t)0.f;                              \
        XBLD[0] = MFMA16(va[0][0], XF[0], XBLD[0]);                            \
        XBLD[1] = MFMA16(va[1][0], XF[0], XBLD[1]);                            \
        XBLD[2] = MFMA16(va[2][0], XF[0], XBLD[2]);                            \
        XBLD[3] = MFMA16(va[3][0], XF[0], XBLD[3]);                            \
        XBLD[0] = MFMA16(va[0][1], XF[1], XBLD[0]);                            \
        XBLD[1] = MFMA16(va[1][1], XF[1], XBLD[1]);                            \
        XBLD[2] = MFMA16(va[2][1], XF[1], XBLD[2]);                            \
        XBLD[3] = MFMA16(va[3][1], XF[1], XBLD[3]);                            \
        XBLD[0] = MFMA16(va[0][2], XF[2], XBLD[0]);                            \
        XBLD[1] = MFMA16(va[1][2], XF[2], XBLD[1]);                            \
        XBLD[2] = MFMA16(va[2][2], XF[2], XBLD[2]);                            \
        XBLD[3] = MFMA16(va[3][2], XF[2], XBLD[3]);                            \
        XBLD[0] = MFMA16(va[0][3], XF[3], XBLD[0]);                            \
        XBLD[1] = MFMA16(va[1][3], XF[3], XBLD[1]);                            \
        XBLD[2] = MFMA16(va[2][3], XF[3], XBLD[2]);                            \
        XBLD[3] = MFMA16(va[3][3], XF[3], XBLD[3]);                            \
        /* shadow: refill XF <- x(SN), consumed 2 steps from now */            \
        {                                                                      \
            const _Float16* q = (const _Float16*)xp + (long)(SN) * xstep;      \
            XF[0] = *(const h8_t*)(q);                                         \
            XF[1] = *(const h8_t*)(q + 32);                                    \
            XF[2] = *(const h8_t*)(q + 64);                                    \
            XF[3] = *(const h8_t*)(q + 96);                                    \
        }                                                                      \
        /* critical tail: select own row rg, +bias, activations */             \
        float v01, v23;                                                        \
        v01 = sel1 ? g0[1] : g0[0];  v23 = sel1 ? g0[3] : g0[2];               \
        float pi = (sel2 ? v23 : v01) + bias[0];                               \
        v01 = sel1 ? g1[1] : g1[0];  v23 = sel1 ? g1[3] : g1[2];               \
        float pf = (sel2 ? v23 : v01) + bias[1];                               \
        v01 = sel1 ? g2[1] : g2[0];  v23 = sel1 ? g2[3] : g2[2];               \
        float pg = (sel2 ? v23 : v01) + bias[2];                               \
        v01 = sel1 ? g3[1] : g3[0];  v23 = sel1 ? g3[3] : g3[2];               \
        float po = (sel2 ? v23 : v01) + bias[3];                               \
        float ia = fsig(pi);                                                   \
        float fa = fsig(pf);                                                   \
        float ga = ftanh(pg);                                                  \
        float oa = fsig(po);                                                   \
        c = fa * c + ia * ga;                                                  \
        float hv = oa * ftanh(c);                                              \
        hlast = hv;                                                            \
        if (col < 4) {                                                         \
            h_buf[(s + 1) & 1][hid] = __float2half(hv);                        \
            *outp = hv;                                                        \
        }                                                                      \
        outp += BATCH * HID;                                                   \
        bar();                                                                 \
    }

__global__ __launch_bounds__(512, 2)
void lstm_scan(const __half* __restrict__ x16, const float* __restrict__ W,
               const float* __restrict__ V, const float* __restrict__ b,
               const float* __restrict__ b2, float* __restrict__ out)
{
    const int bidx = blockIdx.x;
    const int t    = threadIdx.x;
    const int w    = t >> 6;      // wave 0..7 -> hids [16w, 16w+16)
    const int lane = t & 63;
    const int col  = lane & 15;   // MFMA A-row / C-col index
    const int quad = lane >> 4;   // k-slice index; C rows quad*4+{0..3}
    const int rg   = col & 3;     // the C-row this lane activates
    const int hid  = 16 * w + quad * 4 + rg;

    __shared__ __align__(16) __half h_buf[2][HID];   // 512 B

    // W and V fragments, held in regs for the whole scan (64 + 64 VGPRs):
    // a[g][kc][j]  = (f16) W[g*128 + 16w + col][kc*32 + quad*8 + j]
    // va[g][kc][j] = (f16) V[g*128 + 16w + col][kc*32 + quad*8 + j]
    h8_t a[4][4], va[4][4];
#pragma unroll
    for (int g = 0; g < 4; ++g) {
        const float* Wr = W + (long)(g * 128 + 16 * w + col) * 128 + quad * 8;
        const float* Vr = V + (long)(g * 128 + 16 * w + col) * 128 + quad * 8;
#pragma unroll
        for (int kc = 0; kc < 4; ++kc) {
            const float4* wp = (const float4*)(Wr + kc * 32);
            float4 w0 = wp[0], w1 = wp[1];
            a[g][kc] = h8_t{ (_Float16)w0.x, (_Float16)w0.y, (_Float16)w0.z, (_Float16)w0.w,
                             (_Float16)w1.x, (_Float16)w1.y, (_Float16)w1.z, (_Float16)w1.w };
            const float4* vp = (const float4*)(Vr + kc * 32);
            float4 u0 = vp[0], u1 = vp[1];
            va[g][kc] = h8_t{ (_Float16)u0.x, (_Float16)u0.y, (_Float16)u0.z, (_Float16)u0.w,
                              (_Float16)u1.x, (_Float16)u1.y, (_Float16)u1.z, (_Float16)u1.w };
        }
    }

    // per-lane bias for the row this lane activates (added after select)
    float bias[4];
#pragma unroll
    for (int g = 0; g < 4; ++g)
        bias[g] = b[g * 128 + hid] + b2[g * 128 + hid];

    if (t < HID) h_buf[0][t] = __float2half(0.f);
    __syncthreads();

    // x16 frags: lane needs x[s][bidx][kc*32 + quad*8 + {0..7}]
    const _Float16* xp = (const _Float16*)x16 + (long)bidx * 128 + quad * 8;
    const long xstep = (long)BATCH * 128;   // halves per step

    // 2-slot x frag ring: xfE = even steps' x, xfO = odd steps' x
    h8_t xfE[4], xfO[4];
#pragma unroll
    for (int kc = 0; kc < 4; ++kc) {
        xfE[kc] = *(const h8_t*)(xp + kc * 32);             // x(0)
        xfO[kc] = *(const h8_t*)(xp + xstep + kc * 32);     // x(1)
    }

    // prologue: xA = V.x(0); then refill xfE <- x(2)
    f4_t xA[4], xB[4];
#pragma unroll
    for (int g = 0; g < 4; ++g) xA[g] = (f4_t)0.f;
#pragma unroll
    for (int kc = 0; kc < 4; ++kc) {
        xA[0] = MFMA16(va[0][kc], xfE[kc], xA[0]);
        xA[1] = MFMA16(va[1][kc], xfE[kc], xA[1]);
        xA[2] = MFMA16(va[2][kc], xfE[kc], xA[2]);
        xA[3] = MFMA16(va[3][kc], xfE[kc], xA[3]);
    }
#pragma unroll
    for (int kc = 0; kc < 4; ++kc)
        xfE[kc] = *(const h8_t*)(xp + 2 * xstep + kc * 32); // x(2)

    float c = 0.f, hlast = 0.f;
    float* outp = out + (long)bidx * HID + hid;   // col<4 lanes write *outp
    const long SBH = (long)S_LEN * BATCH * HID;
    const bool sel1 = (col & 1) != 0;
    const bool sel2 = (col & 2) != 0;

    for (int s0 = 0; s0 < S_LEN; s0 += 2) {
        int sn0 = s0 + 3; if (sn0 > S_LEN - 1) sn0 = S_LEN - 1;
        LSTEP(s0,     xA, xB, xfO, sn0);   // uses x(s0) acc; builds from x(s0+1)
        int sn1 = s0 + 4; if (sn1 > S_LEN - 1) sn1 = S_LEN - 1;
        LSTEP(s0 + 1, xB, xA, xfE, sn1);   // uses x(s0+1) acc; builds from x(s0+2)
    }

    if (col < 4) {
        out[SBH + (long)bidx * HID + hid]                     = hlast;  // h_T
        out[SBH + (long)BATCH * HID + (long)bidx * HID + hid] = c;      // c_T
    }
}

// ---------------------------------------------------------------------------
extern "C" void kernel_launch(void* const* d_in, const int* in_sizes, int n_in,
                              void* d_out, int out_size, void* d_ws, size_t ws_size,
                              hipStream_t stream) {
    const float* x  = (const float*)d_in[0];
    const float* V  = (const float*)d_in[1];
    const float* W  = (const float*)d_in[2];
    const float* b  = (const float*)d_in[3];
    const float* b2 = (const float*)d_in[4];
    float* out = (float*)d_out;
    __half* x16 = (__half*)d_ws;   // 2048*128*128*2 = 67 MB

    // 33,554,432 elems / (256 thr * 8 per thr) = 16384 blocks
    x_cvt<<<dim3(16384), dim3(256), 0, stream>>>(x, x16);
    lstm_scan<<<dim3(BATCH), dim3(512), 0, stream>>>(x16, W, V, b, b2, out);
}

// Round 5
// 1377.549 us; speedup vs baseline: 1.1668x; 1.1668x over previous
//
#include <hip/hip_runtime.h>
#include <hip/hip_bf16.h>
#include <hip/hip_fp16.h>

// LSTM: S=2048, B=128, I=128, H=128, 4H=512
// out = [h_seq (S*B*H) | h_T (B*H) | c_T (B*H)], fp32
// ws  = xg (S*B*512) fp16 = 268 MB
//
// Round 5 = Round 4 with the double-bias bug fixed:
//   bias lives ONLY in the scan's MFMA C-seed (bias4); xg_gemm no longer
//   adds b+b2 in its epilogue.
// Structure (from R4): xg consume moved OFF the vmcnt domain.
//  - xg staged in 16-step (16 KB) LDS chunks, double-buffered. Each wave
//    loads its 2x16B of chunk c+2 at the end of chunk c (16-step slack,
//    compiler-counted vmcnt), ds_writes chunk c+1 right before the
//    chunk-boundary barrier (lgkm drain publishes it for free).
//  - Per-step consume: 4x ds_read_u16 (lgkm, overlapped with h-frag reads).
//  - Only per-step vmem op: the fire-and-forget h_seq store.

#define S_LEN 2048
#define BATCH 128
#define HID   128
#define G4    512

typedef _Float16 h8_t __attribute__((ext_vector_type(8)));
typedef float    f4_t __attribute__((ext_vector_type(4)));

#define MFMA16(A, B, C) __builtin_amdgcn_mfma_f32_16x16x32_f16((A), (B), (C), 0, 0, 0)

// ---------------------------------------------------------------------------
// Phase 1: xg[m][n] = sum_k x[m][k]*V[n][k]  (NO bias here -- scan seeds it)
// ---------------------------------------------------------------------------
__global__ __launch_bounds__(256, 2)
void xg_gemm(const float* __restrict__ x, const float* __restrict__ V,
             __half* __restrict__ xg)
{
    __shared__ h8_t As[128 * 16];   // 32 KB
    __shared__ h8_t Bs[128 * 16];   // 32 KB

    const int t  = threadIdx.x;
    const int m0 = blockIdx.y * 128;
    const int n0 = blockIdx.x * 128;

#pragma unroll
    for (int r = 0; r < 8; ++r) {
        int id  = t + 256 * r;
        int row = id >> 4;
        int j   = id & 15;
        const float4* gx = (const float4*)(x + (long)(m0 + row) * 128 + j * 8);
        float4 a0 = gx[0], a1 = gx[1];
        h8_t ha = { (_Float16)a0.x, (_Float16)a0.y, (_Float16)a0.z, (_Float16)a0.w,
                    (_Float16)a1.x, (_Float16)a1.y, (_Float16)a1.z, (_Float16)a1.w };
        As[row * 16 + (j ^ (row & 15))] = ha;
        const float4* gv = (const float4*)(V + (long)(n0 + row) * 128 + j * 8);
        float4 b0 = gv[0], b1 = gv[1];
        h8_t hb = { (_Float16)b0.x, (_Float16)b0.y, (_Float16)b0.z, (_Float16)b0.w,
                    (_Float16)b1.x, (_Float16)b1.y, (_Float16)b1.z, (_Float16)b1.w };
        Bs[row * 16 + (j ^ (row & 15))] = hb;
    }
    __syncthreads();

    const int w    = t >> 6;
    const int lane = t & 63;
    const int m    = lane & 15;
    const int quad = lane >> 4;

    f4_t acc[2][8];
#pragma unroll
    for (int i = 0; i < 2; ++i)
#pragma unroll
        for (int j = 0; j < 8; ++j) acc[i][j] = (f4_t)0.f;

#pragma unroll
    for (int ks = 0; ks < 4; ++ks) {
        int ch = ks * 4 + quad;
        h8_t a0 = As[(w * 32      + m) * 16 + (ch ^ m)];
        h8_t a1 = As[(w * 32 + 16 + m) * 16 + (ch ^ m)];
#pragma unroll
        for (int nt = 0; nt < 8; ++nt) {
            h8_t bf = Bs[(nt * 16 + m) * 16 + (ch ^ m)];
            acc[0][nt] = MFMA16(a0, bf, acc[0][nt]);
            acc[1][nt] = MFMA16(a1, bf, acc[1][nt]);
        }
    }

#pragma unroll
    for (int nt = 0; nt < 8; ++nt) {
        int col = n0 + nt * 16 + m;
#pragma unroll
        for (int mi = 0; mi < 2; ++mi) {
#pragma unroll
            for (int rg = 0; rg < 4; ++rg) {
                long mrow = (long)(m0 + w * 32 + mi * 16 + quad * 4 + rg);
                xg[mrow * G4 + col] = __float2half(acc[mi][nt][rg]);
            }
        }
    }
}

// ---------------------------------------------------------------------------
__device__ __forceinline__ float fsig(float x) {
    return __builtin_amdgcn_rcpf(1.f + __expf(-x));
}
__device__ __forceinline__ float ftanh(float x) {
    return 1.f - 2.f * __builtin_amdgcn_rcpf(1.f + __expf(2.f * x));
}
__device__ __forceinline__ void bar() {
    asm volatile("s_waitcnt lgkmcnt(0)" ::: "memory");
    __builtin_amdgcn_s_barrier();
    asm volatile("" ::: "memory");
}

#define CHUNK 16                         // steps per LDS chunk
#define NCHUNK (S_LEN / CHUNK)           // 128

__global__ __launch_bounds__(512, 2)
void lstm_scan(const __half* __restrict__ xg, const float* __restrict__ W,
               const float* __restrict__ b, const float* __restrict__ b2,
               float* __restrict__ out)
{
    const int bidx = blockIdx.x;
    const int t    = threadIdx.x;
    const int w    = t >> 6;      // wave 0..7 -> hids [16w, 16w+16)
    const int lane = t & 63;
    const int col  = lane & 15;   // MFMA A-row / C-col index
    const int quad = lane >> 4;   // k-slice index; C rows quad*4+{0..3}
    const int rg   = col & 3;     // the C-row this lane activates
    const int hid  = 16 * w + quad * 4 + rg;

    __shared__ __align__(16) __half xgb[2][CHUNK][G4];   // 32 KB
    __shared__ __align__(16) __half h_buf[2][HID];       // 512 B

    // W fragments: a[g][kc][j] = (f16) W[g*128 + 16w + col][kc*32 + quad*8 + j]
    h8_t a[4][4];
#pragma unroll
    for (int g = 0; g < 4; ++g) {
        const float* Wr = W + (long)(g * 128 + 16 * w + col) * 128 + quad * 8;
#pragma unroll
        for (int kc = 0; kc < 4; ++kc) {
            const float4* wp = (const float4*)(Wr + kc * 32);
            float4 w0 = wp[0], w1 = wp[1];
            a[g][kc] = h8_t{ (_Float16)w0.x, (_Float16)w0.y, (_Float16)w0.z, (_Float16)w0.w,
                             (_Float16)w1.x, (_Float16)w1.y, (_Float16)w1.z, (_Float16)w1.w };
        }
    }

    // bias seeds for the MFMA C-input: bias4[g][r] = (b+b2)[g*128+16w+quad*4+r]
    // (the ONLY place bias is applied -- xg is bias-free now)
    f4_t bias4[4];
#pragma unroll
    for (int g = 0; g < 4; ++g)
#pragma unroll
        for (int r = 0; r < 4; ++r) {
            int idx = g * 128 + 16 * w + quad * 4 + r;
            bias4[g][r] = b[idx] + b2[idx];
        }

    // xg staging: wave w owns chunk rows {w, w+8}; 2 x (64 lanes x 16B) per chunk
    const int r0 = w, r1 = w + 8;
    const h8_t* src0 = (const h8_t*)(xg + ((long)r0 * BATCH + bidx) * G4 + lane * 8);
    const h8_t* src1 = (const h8_t*)(xg + ((long)r1 * BATCH + bidx) * G4 + lane * 8);
    const long chunk_stride = (long)CHUNK * BATCH * G4 / 8;   // in h8 units

    h8_t st0 = src0[0], st1 = src1[0];                 // chunk 0
    *(h8_t*)(&xgb[0][r0][lane * 8]) = st0;             // (one-time vmcnt drain)
    *(h8_t*)(&xgb[0][r1][lane * 8]) = st1;
    st0 = src0[chunk_stride];                          // chunk 1
    st1 = src1[chunk_stride];

    if (t < HID) h_buf[0][t] = __float2half(0.f);
    __syncthreads();

    float c = 0.f, hlast = 0.f;
    float* outp = out + (long)bidx * HID + hid;        // col<4 lanes write
    const long SBH = (long)S_LEN * BATCH * HID;
    const bool sel1 = (col & 1) != 0;
    const bool sel2 = (col & 2) != 0;

    for (int ch = 0; ch < NCHUNK; ++ch) {
        const int buf = ch & 1;
#pragma unroll
        for (int sl = 0; sl < CHUNK; ++sl) {
            // h fragments (quad-broadcast, conflict-free); parity = sl&1
            const h8_t* hb = (const h8_t*)(&h_buf[sl & 1][0]);
            h8_t hf0 = hb[quad], hf1 = hb[4 + quad], hf2 = hb[8 + quad],
                 hf3 = hb[12 + quad];

            // xg consume from LDS (lgkm, overlapped with h-frag reads)
            const __half* xr = &xgb[buf][sl][hid];
            float xv0 = __half2float(xr[0]);
            float xv1 = __half2float(xr[128]);
            float xv2 = __half2float(xr[256]);
            float xv3 = __half2float(xr[384]);

            f4_t g0 = bias4[0], g1 = bias4[1], g2 = bias4[2], g3 = bias4[3];
            g0 = MFMA16(a[0][0], hf0, g0);  g1 = MFMA16(a[1][0], hf0, g1);
            g2 = MFMA16(a[2][0], hf0, g2);  g3 = MFMA16(a[3][0], hf0, g3);
            g0 = MFMA16(a[0][1], hf1, g0);  g1 = MFMA16(a[1][1], hf1, g1);
            g2 = MFMA16(a[2][1], hf1, g2);  g3 = MFMA16(a[3][1], hf1, g3);
            g0 = MFMA16(a[0][2], hf2, g0);  g1 = MFMA16(a[1][2], hf2, g1);
            g2 = MFMA16(a[2][2], hf2, g2);  g3 = MFMA16(a[3][2], hf2, g3);
            g0 = MFMA16(a[0][3], hf3, g0);  g1 = MFMA16(a[1][3], hf3, g1);
            g2 = MFMA16(a[2][3], hf3, g2);  g3 = MFMA16(a[3][3], hf3, g3);

            // select own C row (rg = col&3), add xv, activate
            float v01, v23;
            v01 = sel1 ? g0[1] : g0[0];  v23 = sel1 ? g0[3] : g0[2];
            float pi = (sel2 ? v23 : v01) + xv0;
            v01 = sel1 ? g1[1] : g1[0];  v23 = sel1 ? g1[3] : g1[2];
            float pf = (sel2 ? v23 : v01) + xv1;
            v01 = sel1 ? g2[1] : g2[0];  v23 = sel1 ? g2[3] : g2[2];
            float pg = (sel2 ? v23 : v01) + xv2;
            v01 = sel1 ? g3[1] : g3[0];  v23 = sel1 ? g3[3] : g3[2];
            float po = (sel2 ? v23 : v01) + xv3;

            float ia = fsig(pi);
            float fa = fsig(pf);
            float ga = ftanh(pg);
            float oa = fsig(po);
            c = fa * c + ia * ga;             // redundant x4 across col groups
            float hv = oa * ftanh(c);
            hlast = hv;

            if (col < 4) {                    // unique writer per hid
                h_buf[(sl + 1) & 1][hid] = __float2half(hv);
                *outp = hv;                   // fire-and-forget
            }
            outp += BATCH * HID;

            if (sl == CHUNK - 1) {
                // publish chunk ch+1 into the other buffer (drained by bar()),
                // then issue loads for chunk ch+2 (16-step slack, counted vmcnt)
                *(h8_t*)(&xgb[buf ^ 1][r0][lane * 8]) = st0;
                *(h8_t*)(&xgb[buf ^ 1][r1][lane * 8]) = st1;
                long cn = (ch + 2 < NCHUNK) ? (ch + 2) : (NCHUNK - 1);
                st0 = src0[cn * chunk_stride];
                st1 = src1[cn * chunk_stride];
            }
            bar();   // lgkmcnt(0) + s_barrier: h (and staged chunk) visible
        }
    }

    if (col < 4) {
        out[SBH + (long)bidx * HID + hid]                     = hlast;  // h_T
        out[SBH + (long)BATCH * HID + (long)bidx * HID + hid] = c;      // c_T
    }
}

// ---------------------------------------------------------------------------
extern "C" void kernel_launch(void* const* d_in, const int* in_sizes, int n_in,
                              void* d_out, int out_size, void* d_ws, size_t ws_size,
                              hipStream_t stream) {
    const float* x  = (const float*)d_in[0];
    const float* V  = (const float*)d_in[1];
    const float* W  = (const float*)d_in[2];
    const float* b  = (const float*)d_in[3];
    const float* b2 = (const float*)d_in[4];
    float* out = (float*)d_out;
    __half* xg = (__half*)d_ws;   // 2048*128*512*2 = 268435456 B

    dim3 g1(G4 / 128, (S_LEN * BATCH) / 128);   // (4, 2048)
    xg_gemm<<<g1, dim3(256), 0, stream>>>(x, V, xg);
    lstm_scan<<<dim3(BATCH), dim3(512), 0, stream>>>(xg, W, b, b2, out);
}